// Round 20
// baseline (26.632 us; speedup 1.0000x reference)
//
#include <hip/hip_runtime.h>
#include <hip/hip_bf16.h>
#include <math.h>

#define BN 32
#define XLEN 1024
#define COLS 512
#define ROWS (BN * XLEN)   // 32768
#define STAB 1e-15

typedef float v2f __attribute__((ext_vector_type(2)));

// hardware transcendentals via AMDGCN builtins (glibc-collision-free):
//   HW_EXP2(x) = v_exp_f32 = 2^x ;  HW_LOG2(x) = v_log_f32 = log2(x)
#define HW_EXP2(x) __builtin_amdgcn_exp2f(x)
#define HW_LOG2(x) __builtin_amdgcn_logf(x)
#define HW_RCP(x)  __builtin_amdgcn_rcpf(x)

// ---------------------------------------------------------------------------
// Full per-row-set gaus pipeline (identical numerics to round 19, absmax
// 2048): minmax -> exp/sum -> packed f32 moments -> f64 butterfly -> fit.
// PRECISION NOTE (round-14 lesson): per-lane f32 accumulation is tolerated,
// but the cross-lane reduction tree MUST be f64 (formula amplifies error).
// ---------------------------------------------------------------------------
__device__ __forceinline__ void gf_process(v2f ve[16], int sub, int row,
                                           float* __restrict__ mu_out,
                                           float* __restrict__ sig_out) {
  v2f mx2 = ve[0], xn2 = ve[0];
#pragma unroll
  for (int k = 1; k < 16; ++k) {
    mx2 = __builtin_elementwise_max(mx2, ve[k]);
    xn2 = __builtin_elementwise_min(xn2, ve[k]);
  }
  float mx = fmaxf(mx2.x, mx2.y);
  float xn = fminf(xn2.x, xn2.y);
#pragma unroll
  for (int m = 8; m >= 1; m >>= 1) {
    mx = fmaxf(mx, __shfl_xor(mx, m, 64));
    xn = fminf(xn, __shfl_xor(xn, m, 64));
  }

  const float LOG2E = 1.44269504089f;
  const float mxs = mx * LOG2E;
  const v2f L2E2 = {LOG2E, LOG2E};
  const v2f NMXS = {-mxs, -mxs};
  v2f S2a = {0.0f, 0.0f}, S2b = {0.0f, 0.0f};
#pragma unroll
  for (int k = 0; k < 16; k += 2) {
    const v2f xs0 = __builtin_elementwise_fma(ve[k], L2E2, NMXS);
    const v2f xs1 = __builtin_elementwise_fma(ve[k + 1], L2E2, NMXS);
    ve[k].x     = HW_EXP2(xs0.x);
    ve[k].y     = HW_EXP2(xs0.y);
    ve[k + 1].x = HW_EXP2(xs1.x);
    ve[k + 1].y = HW_EXP2(xs1.y);
    S2a += ve[k];
    S2b += ve[k + 1];
  }
  const v2f S2 = S2a + S2b;
  float S = S2.x + S2.y;
#pragma unroll
  for (int m = 8; m >= 1; m >>= 1) S += __shfl_xor(S, m, 64);

  const float invS   = 1.0f / S;
  const float emin   = HW_EXP2(fmaf(xn, LOG2E, -mxs));  // == min over e
  const float pmin   = emin * invS;
  const float pmax   = invS;              // emax = exp(0) = 1 exactly
  const float invden = 1.0f / (pmax - pmin);
  const float CA     = invS * invden;
  const float CB     = fmaf(-pmin, invden, 0.001f);
  const v2f CA2 = {CA, CA}, CB2 = {CB, CB};

  const float bb = (float)(4 * sub) * (1.0f / 512.0f);
  v2f u0 = {0, 0}, u1 = {0, 0}, u2 = {0, 0}, u3 = {0, 0}, u4 = {0, 0};
  v2f w0 = {0, 0}, w1 = {0, 0}, w2 = {0, 0};

#define GF_PAIR(j, h)                                                         \
  {                                                                           \
    const int   k   = 2 * (j) + (h);                                          \
    const float off = (float)(64 * (j) + 2 * (h)) * (1.0f / 512.0f);          \
    const v2f xh = {bb + off, bb + off + 0.001953125f};                       \
    const v2f pn = __builtin_elementwise_fma(ve[k], CA2, CB2);                \
    v2f l2;                                                                   \
    l2.x = HW_LOG2(pn.x);                                                     \
    l2.y = HW_LOG2(pn.y);                                                     \
    const v2f y2  = pn * pn;                                                  \
    const v2f y2l = y2 * l2;                                                  \
    const v2f x2  = xh * xh;                                                  \
    const v2f x3  = x2 * xh;                                                  \
    const v2f x4  = x2 * x2;                                                  \
    u0 += y2;                                                                 \
    u1 = __builtin_elementwise_fma(xh, y2, u1);                               \
    u2 = __builtin_elementwise_fma(x2, y2, u2);                               \
    u3 = __builtin_elementwise_fma(x3, y2, u3);                               \
    u4 = __builtin_elementwise_fma(x4, y2, u4);                               \
    w0 += y2l;                                                                \
    w1 = __builtin_elementwise_fma(xh, y2l, w1);                              \
    w2 = __builtin_elementwise_fma(x2, y2l, w2);                              \
  }

#pragma unroll
  for (int j = 0; j < 8; ++j) {
    GF_PAIR(j, 0)
    GF_PAIR(j, 1)
  }
#undef GF_PAIR

  // per-lane exact f64 hadd of packed sums, then 4-step f64 butterfly
  double d0 = (double)u0.x + (double)u0.y;
  double d1 = (double)u1.x + (double)u1.y;
  double d2 = (double)u2.x + (double)u2.y;
  double d3 = (double)u3.x + (double)u3.y;
  double d4 = (double)u4.x + (double)u4.y;
  double e0 = (double)w0.x + (double)w0.y;
  double e1 = (double)w1.x + (double)w1.y;
  double e2 = (double)w2.x + (double)w2.y;
#pragma unroll
  for (int m = 8; m >= 1; m >>= 1) {
    d0 += __shfl_xor(d0, m, 64);
    d1 += __shfl_xor(d1, m, 64);
    d2 += __shfl_xor(d2, m, 64);
    d3 += __shfl_xor(d3, m, 64);
    d4 += __shfl_xor(d4, m, 64);
    e0 += __shfl_xor(e0, m, 64);
    e1 += __shfl_xor(e1, m, 64);
    e2 += __shfl_xor(e2, m, 64);
  }

  if (sub == 0) {   // lanes 0,16,32,48 — one per row
    const double LN2D = 0.6931471805599453;
    const double s_y2    = d0;
    const double s_xy2   = d1 * 512.0;
    const double s_x2y2  = d2 * 262144.0;            // 512^2
    const double s_x3y2  = d3 * 134217728.0;         // 512^3
    const double s_x4y2  = d4 * 68719476736.0;       // 512^4
    const double s_y2l   = e0 * LN2D;
    const double s_xy2l  = (e1 * 512.0) * LN2D;
    const double s_x2y2l = (e2 * 262144.0) * LN2D;
    const double A2 = s_x2y2 * s_x2y2;
    double b_num = A2 * s_xy2l - s_y2 * s_x4y2 * s_xy2l
                 + s_xy2 * s_x4y2 * s_y2l + s_y2 * s_x3y2 * s_x2y2l
                 - s_x2y2 * s_x3y2 * s_y2l - s_xy2 * s_x2y2 * s_x2y2l;
    double c_num = s_x2y2l * s_xy2 * s_xy2 - s_xy2l * s_xy2 * s_x2y2
                 - s_x3y2 * s_y2l * s_xy2 + s_y2l * A2
                 - s_y2 * s_x2y2l * s_x2y2 + s_y2 * s_x3y2 * s_xy2l;
    if (fabs(c_num) < STAB) {
      c_num = (c_num > 0.0) ? STAB : ((c_num < 0.0) ? -STAB : 0.0);
    }
    const double mu = -b_num / (2.0 * c_num);
    const double c_din = s_x4y2 * s_xy2 * s_xy2
                       - 2.0 * s_xy2 * s_x2y2 * s_x3y2 + s_x2y2 * A2
                       - s_y2 * s_x4y2 * s_x2y2 + s_y2 * s_x3y2 * s_x3y2;
    double sigma = -0.5 * c_din / c_num;
    if (sigma < 1.0) sigma = 1.0;  // NaN stays NaN, matching jnp.where
    mu_out[row]  = (float)mu;
    sig_out[row] = (float)sigma;
  }
}

// ---------------------------------------------------------------------------
// Kernel 1: 2-deep software-pipelined gaus fit. Each wave owns 8 rows (two
// sets of 4); BOTH sets' loads are issued up front, so set B's 8 dwordx4
// loads stay in flight (vmcnt(8)) under set A's entire compute pipeline —
// attacking the measured compute/memory serialization (18us ~= 8us VALU +
// 10us BW, unoverlapped). Grid 1024 blocks (4/CU). Per-row numerics
// byte-identical to round 19.
// ---------------------------------------------------------------------------
__global__ __launch_bounds__(256) void gaus_fit_kernel(
    const float* __restrict__ x, float* __restrict__ mu_out,
    float* __restrict__ sig_out) {
  const int lane = threadIdx.x & 63;
  const int wid  = threadIdx.x >> 6;   // wave 0..3 in block
  const int sub  = lane & 15;          // lane within row-group
  const int rowA = blockIdx.x * 32 + wid * 8 + (lane >> 4);
  const int rowB = rowA + 4;

  const v2f* rpA = (const v2f*)(x + (size_t)rowA * COLS);
  const v2f* rpB = (const v2f*)(x + (size_t)rowB * COLS);
  v2f veA[16], veB[16];
#pragma unroll
  for (int j = 0; j < 8; ++j) {
    veA[2 * j]     = rpA[32 * j + 2 * sub];
    veA[2 * j + 1] = rpA[32 * j + 2 * sub + 1];
  }
#pragma unroll
  for (int j = 0; j < 8; ++j) {
    veB[2 * j]     = rpB[32 * j + 2 * sub];
    veB[2 * j + 1] = rpB[32 * j + 2 * sub + 1];
  }

  gf_process(veA, sub, rowA, mu_out, sig_out);   // B loads still in flight
  gf_process(veB, sub, rowB, mu_out, sig_out);
}

// ---------------------------------------------------------------------------
// Kernel 2: per-batch tridiagonal solve via parallel cyclic reduction, f32.
// (Byte-identical to round 19, which passed.)
// ---------------------------------------------------------------------------
__global__ __launch_bounds__(1024) void pcr_solve_kernel(
    const float* __restrict__ mu, const float* __restrict__ sigma,
    const float* __restrict__ w_comp, float* __restrict__ out) {
  __shared__ float A[2][XLEN], B[2][XLEN], C[2][XLEN], D[2][XLEN];
  const int i = threadIdx.x;
  const int g = blockIdx.x * XLEN + i;

  const float w = w_comp[0];
  const float offf  = -2.0f * w;
  const float mainw = (i == 0 || i == XLEN - 1) ? (2.0f * w) : (4.0f * w);
  const float sr = 1.0f / sigma[g];      // f32, matches reference
  const float bf = mainw + sr;           // f32 diag entry
  const float df = mu[g] * sr;           // f32 rhs

  A[0][i] = (i == 0) ? 0.0f : offf;
  C[0][i] = (i == XLEN - 1) ? 0.0f : offf;
  B[0][i] = bf;
  D[0][i] = df;
  __syncthreads();

  int cur = 0;
  for (int s = 1; s < XLEN; s <<= 1) {
    const float ai = A[cur][i], bi = B[cur][i], ci = C[cur][i], di = D[cur][i];
    float am = 0.0f, cm = 0.0f, dm = 0.0f, rm = 0.0f;
    float ap = 0.0f, cp = 0.0f, dp = 0.0f, rp = 0.0f;
    if (i >= s) {
      am = A[cur][i - s]; cm = C[cur][i - s]; dm = D[cur][i - s];
      rm = HW_RCP(B[cur][i - s]);
    }
    if (i + s < XLEN) {
      ap = A[cur][i + s]; cp = C[cur][i + s]; dp = D[cur][i + s];
      rp = HW_RCP(B[cur][i + s]);
    }
    const float k1 = ai * rm;   // rm/rp are 0 when guarded out
    const float k2 = ci * rp;
    const float nb = bi - k1 * cm - k2 * ap;
    const float nd = di - k1 * dm - k2 * dp;
    const int nxt = cur ^ 1;
    A[nxt][i] = -k1 * am;
    C[nxt][i] = -k2 * cp;
    B[nxt][i] = nb;
    D[nxt][i] = nd;
    __syncthreads();
    cur = nxt;
  }

  out[g] = D[cur][i] / B[cur][i];
}

extern "C" void kernel_launch(void* const* d_in, const int* in_sizes, int n_in,
                              void* d_out, int out_size, void* d_ws, size_t ws_size,
                              hipStream_t stream) {
  const float* x      = (const float*)d_in[0];
  const float* w_comp = (const float*)d_in[1];
  float* out = (float*)d_out;

  float* mu_ws  = (float*)d_ws;
  float* sig_ws = mu_ws + ROWS;

  gaus_fit_kernel<<<ROWS / 32, 256, 0, stream>>>(x, mu_ws, sig_ws);
  pcr_solve_kernel<<<BN, XLEN, 0, stream>>>(mu_ws, sig_ws, w_comp, out);
}

// Round 21
// 24.338 us; speedup vs baseline: 1.0942x; 1.0942x over previous
//
#include <hip/hip_runtime.h>
#include <hip/hip_bf16.h>
#include <math.h>

#define BN 32
#define XLEN 1024
#define COLS 512
#define ROWS (BN * XLEN)   // 32768
#define STAB 1e-15

typedef float v2f __attribute__((ext_vector_type(2)));

// hardware transcendentals via AMDGCN builtins (glibc-collision-free):
//   HW_EXP2(x) = v_exp_f32 = 2^x ;  HW_LOG2(x) = v_log_f32 = log2(x)
#define HW_EXP2(x) __builtin_amdgcn_exp2f(x)
#define HW_LOG2(x) __builtin_amdgcn_logf(x)
#define HW_RCP(x)  __builtin_amdgcn_rcpf(x)

// ---------------------------------------------------------------------------
// DPP rotate helpers: row_ror:N rotates within each 16-lane row on the VALU
// pipe (no LDS traffic, 1-2 cycle forwarding). Rotate-reduce over N=8,4,2,1
// gives every lane of a 16-lane group the full group reduction — same result
// class as the previous __shfl_xor butterfly (exact for min/max; reorder-only
// for sums: f32 S is the accepted 1-ulp family, f64 sums ~1e-16).
// DPP ctrl: ROW_ROR_N = 0x120 + N.
// ---------------------------------------------------------------------------
template <int CTRL>
__device__ __forceinline__ float dpp_rot_f32(float v) {
  return __int_as_float(__builtin_amdgcn_mov_dpp(
      __float_as_int(v), CTRL, 0xF, 0xF, false));
}
template <int CTRL>
__device__ __forceinline__ double dpp_rot_f64(double v) {
  const unsigned long long u = __double_as_longlong(v);
  const int lo = __builtin_amdgcn_mov_dpp((int)(u & 0xFFFFFFFFull),
                                          CTRL, 0xF, 0xF, false);
  const int hi = __builtin_amdgcn_mov_dpp((int)(u >> 32),
                                          CTRL, 0xF, 0xF, false);
  return __longlong_as_double(((unsigned long long)(unsigned)hi << 32) |
                              (unsigned)lo);
}
#define ROR8 0x128
#define ROR4 0x124
#define ROR2 0x122
#define ROR1 0x121

__device__ __forceinline__ float dpp_sum16_f32(float v) {
  v += dpp_rot_f32<ROR8>(v);
  v += dpp_rot_f32<ROR4>(v);
  v += dpp_rot_f32<ROR2>(v);
  v += dpp_rot_f32<ROR1>(v);
  return v;
}
__device__ __forceinline__ float dpp_max16_f32(float v) {
  v = fmaxf(v, dpp_rot_f32<ROR8>(v));
  v = fmaxf(v, dpp_rot_f32<ROR4>(v));
  v = fmaxf(v, dpp_rot_f32<ROR2>(v));
  v = fmaxf(v, dpp_rot_f32<ROR1>(v));
  return v;
}
__device__ __forceinline__ float dpp_min16_f32(float v) {
  v = fminf(v, dpp_rot_f32<ROR8>(v));
  v = fminf(v, dpp_rot_f32<ROR4>(v));
  v = fminf(v, dpp_rot_f32<ROR2>(v));
  v = fminf(v, dpp_rot_f32<ROR1>(v));
  return v;
}
__device__ __forceinline__ double dpp_sum16_f64(double v) {
  v += dpp_rot_f64<ROR8>(v);
  v += dpp_rot_f64<ROR4>(v);
  v += dpp_rot_f64<ROR2>(v);
  v += dpp_rot_f64<ROR1>(v);
  return v;
}

// ---------------------------------------------------------------------------
// Kernel 1: softmax (f32) -> min-max normalize (f32) -> weighted Gaussian fit.
// Round-19 structure (best measured: 25.38 us, absmax 2048): 4 rows/wave,
// 16 lanes/row, 32 cols/lane (16 packed pairs), 4 waves per 256-thread block,
// grid 2048. This round: ALL reductions via DPP row_ror rotate-reduce (VALU
// pipe) instead of __shfl_xor (ds_bpermute on the contended LDS pipe with
// 4-deep serial latency chains).
// PRECISION NOTE (round-14 lesson): per-lane f32 accumulation is tolerated,
// but the cross-lane reduction tree MUST be f64 (formula amplifies error).
// FUSION NOTE (round-18): do not fuse PCR (regalloc collapse -> spill, 4x).
// PIPELINE NOTE (round-20): 2-deep row pipelining costs occupancy, -5%.
// ---------------------------------------------------------------------------
__global__ __launch_bounds__(256) void gaus_fit_kernel(
    const float* __restrict__ x, float* __restrict__ mu_out,
    float* __restrict__ sig_out) {
  const int lane = threadIdx.x & 63;
  const int wid  = threadIdx.x >> 6;   // wave 0..3 in block
  const int sub  = lane & 15;          // lane within row-group
  const int row  = blockIdx.x * 16 + wid * 4 + (lane >> 4);

  // Each lane: 16 v2f loads (adjacent pairs merge to dwordx4); pair k=2j+h
  // covers cols 64*j + 4*sub + {2h, 2h+1}.
  const v2f* rp2 = (const v2f*)(x + (size_t)row * COLS);
  v2f ve[16];
#pragma unroll
  for (int j = 0; j < 8; ++j) {
    ve[2 * j]     = rp2[32 * j + 2 * sub];
    ve[2 * j + 1] = rp2[32 * j + 2 * sub + 1];
  }

  // packed min/max of raw x, then component + 16-lane DPP reduce
  v2f mx2 = ve[0], xn2 = ve[0];
#pragma unroll
  for (int k = 1; k < 16; ++k) {
    mx2 = __builtin_elementwise_max(mx2, ve[k]);
    xn2 = __builtin_elementwise_min(xn2, ve[k]);
  }
  const float mx = dpp_max16_f32(fmaxf(mx2.x, mx2.y));
  const float xn = dpp_min16_f32(fminf(xn2.x, xn2.y));

  // pass A: e = exp2(fma(x, log2e, -mxs)) overwrites ve in place; packed sum
  const float LOG2E = 1.44269504089f;
  const float mxs = mx * LOG2E;
  const v2f L2E2 = {LOG2E, LOG2E};
  const v2f NMXS = {-mxs, -mxs};
  v2f S2a = {0.0f, 0.0f}, S2b = {0.0f, 0.0f};
#pragma unroll
  for (int k = 0; k < 16; k += 2) {
    const v2f xs0 = __builtin_elementwise_fma(ve[k], L2E2, NMXS);
    const v2f xs1 = __builtin_elementwise_fma(ve[k + 1], L2E2, NMXS);
    ve[k].x     = HW_EXP2(xs0.x);
    ve[k].y     = HW_EXP2(xs0.y);
    ve[k + 1].x = HW_EXP2(xs1.x);
    ve[k + 1].y = HW_EXP2(xs1.y);
    S2a += ve[k];
    S2b += ve[k + 1];
  }
  const v2f S2 = S2a + S2b;
  const float S = dpp_sum16_f32(S2.x + S2.y);

  const float invS   = 1.0f / S;
  const float emin   = HW_EXP2(fmaf(xn, LOG2E, -mxs));  // == min over e
  const float pmin   = emin * invS;
  const float pmax   = invS;              // emax = exp(0) = 1 exactly
  const float invden = 1.0f / (pmax - pmin);
  const float CA     = invS * invden;
  const float CB     = fmaf(-pmin, invden, 0.001f);
  const v2f CA2 = {CA, CA}, CB2 = {CB, CB};

  // pass B: packed f32 moment accumulation with raw log2.
  // xh per pair = bb + compile-time-constant offset (exact): no serial chain.
  const float bb = (float)(4 * sub) * (1.0f / 512.0f);
  v2f u0 = {0, 0}, u1 = {0, 0}, u2 = {0, 0}, u3 = {0, 0}, u4 = {0, 0};
  v2f w0 = {0, 0}, w1 = {0, 0}, w2 = {0, 0};

#define GF_PAIR(j, h)                                                         \
  {                                                                           \
    const int   k   = 2 * (j) + (h);                                          \
    const float off = (float)(64 * (j) + 2 * (h)) * (1.0f / 512.0f);          \
    const v2f xh = {bb + off, bb + off + 0.001953125f};                       \
    const v2f pn = __builtin_elementwise_fma(ve[k], CA2, CB2);                \
    v2f l2;                                                                   \
    l2.x = HW_LOG2(pn.x);                                                     \
    l2.y = HW_LOG2(pn.y);                                                     \
    const v2f y2  = pn * pn;                                                  \
    const v2f y2l = y2 * l2;                                                  \
    const v2f x2  = xh * xh;                                                  \
    const v2f x3  = x2 * xh;                                                  \
    const v2f x4  = x2 * x2;                                                  \
    u0 += y2;                                                                 \
    u1 = __builtin_elementwise_fma(xh, y2, u1);                               \
    u2 = __builtin_elementwise_fma(x2, y2, u2);                               \
    u3 = __builtin_elementwise_fma(x3, y2, u3);                               \
    u4 = __builtin_elementwise_fma(x4, y2, u4);                               \
    w0 += y2l;                                                                \
    w1 = __builtin_elementwise_fma(xh, y2l, w1);                              \
    w2 = __builtin_elementwise_fma(x2, y2l, w2);                              \
  }

#pragma unroll
  for (int j = 0; j < 8; ++j) {
    GF_PAIR(j, 0)
    GF_PAIR(j, 1)
  }
#undef GF_PAIR

  // per-lane exact f64 hadd, then 16-lane DPP rotate-reduce in f64
  // (f64 REQUIRED here — see precision note above)
  const double d0 = dpp_sum16_f64((double)u0.x + (double)u0.y);
  const double d1 = dpp_sum16_f64((double)u1.x + (double)u1.y);
  const double d2 = dpp_sum16_f64((double)u2.x + (double)u2.y);
  const double d3 = dpp_sum16_f64((double)u3.x + (double)u3.y);
  const double d4 = dpp_sum16_f64((double)u4.x + (double)u4.y);
  const double e0 = dpp_sum16_f64((double)w0.x + (double)w0.y);
  const double e1 = dpp_sum16_f64((double)w1.x + (double)w1.y);
  const double e2 = dpp_sum16_f64((double)w2.x + (double)w2.y);

  if (sub == 0) {   // lanes 0,16,32,48 — one per row
    const double LN2D = 0.6931471805599453;
    // unscale by exact 512^k; apply ln2 to the log2-sums (one rounding each)
    const double s_y2    = d0;
    const double s_xy2   = d1 * 512.0;
    const double s_x2y2  = d2 * 262144.0;            // 512^2
    const double s_x3y2  = d3 * 134217728.0;         // 512^3
    const double s_x4y2  = d4 * 68719476736.0;       // 512^4
    const double s_y2l   = e0 * LN2D;
    const double s_xy2l  = (e1 * 512.0) * LN2D;
    const double s_x2y2l = (e2 * 262144.0) * LN2D;
    const double A2 = s_x2y2 * s_x2y2;
    double b_num = A2 * s_xy2l - s_y2 * s_x4y2 * s_xy2l
                 + s_xy2 * s_x4y2 * s_y2l + s_y2 * s_x3y2 * s_x2y2l
                 - s_x2y2 * s_x3y2 * s_y2l - s_xy2 * s_x2y2 * s_x2y2l;
    double c_num = s_x2y2l * s_xy2 * s_xy2 - s_xy2l * s_xy2 * s_x2y2
                 - s_x3y2 * s_y2l * s_xy2 + s_y2l * A2
                 - s_y2 * s_x2y2l * s_x2y2 + s_y2 * s_x3y2 * s_xy2l;
    if (fabs(c_num) < STAB) {
      c_num = (c_num > 0.0) ? STAB : ((c_num < 0.0) ? -STAB : 0.0);
    }
    const double mu = -b_num / (2.0 * c_num);
    const double c_din = s_x4y2 * s_xy2 * s_xy2
                       - 2.0 * s_xy2 * s_x2y2 * s_x3y2 + s_x2y2 * A2
                       - s_y2 * s_x4y2 * s_x2y2 + s_y2 * s_x3y2 * s_x3y2;
    double sigma = -0.5 * c_din / c_num;
    if (sigma < 1.0) sigma = 1.0;  // NaN stays NaN, matching jnp.where
    mu_out[row]  = (float)mu;
    sig_out[row] = (float)sigma;
  }
}

// ---------------------------------------------------------------------------
// Kernel 2: per-batch tridiagonal solve via parallel cyclic reduction, f32.
// (Byte-identical to round 19, which passed.)
// ---------------------------------------------------------------------------
__global__ __launch_bounds__(1024) void pcr_solve_kernel(
    const float* __restrict__ mu, const float* __restrict__ sigma,
    const float* __restrict__ w_comp, float* __restrict__ out) {
  __shared__ float A[2][XLEN], B[2][XLEN], C[2][XLEN], D[2][XLEN];
  const int i = threadIdx.x;
  const int g = blockIdx.x * XLEN + i;

  const float w = w_comp[0];
  const float offf  = -2.0f * w;
  const float mainw = (i == 0 || i == XLEN - 1) ? (2.0f * w) : (4.0f * w);
  const float sr = 1.0f / sigma[g];      // f32, matches reference
  const float bf = mainw + sr;           // f32 diag entry
  const float df = mu[g] * sr;           // f32 rhs

  A[0][i] = (i == 0) ? 0.0f : offf;
  C[0][i] = (i == XLEN - 1) ? 0.0f : offf;
  B[0][i] = bf;
  D[0][i] = df;
  __syncthreads();

  int cur = 0;
  for (int s = 1; s < XLEN; s <<= 1) {
    const float ai = A[cur][i], bi = B[cur][i], ci = C[cur][i], di = D[cur][i];
    float am = 0.0f, cm = 0.0f, dm = 0.0f, rm = 0.0f;
    float ap = 0.0f, cp = 0.0f, dp = 0.0f, rp = 0.0f;
    if (i >= s) {
      am = A[cur][i - s]; cm = C[cur][i - s]; dm = D[cur][i - s];
      rm = HW_RCP(B[cur][i - s]);
    }
    if (i + s < XLEN) {
      ap = A[cur][i + s]; cp = C[cur][i + s]; dp = D[cur][i + s];
      rp = HW_RCP(B[cur][i + s]);
    }
    const float k1 = ai * rm;   // rm/rp are 0 when guarded out
    const float k2 = ci * rp;
    const float nb = bi - k1 * cm - k2 * ap;
    const float nd = di - k1 * dm - k2 * dp;
    const int nxt = cur ^ 1;
    A[nxt][i] = -k1 * am;
    C[nxt][i] = -k2 * cp;
    B[nxt][i] = nb;
    D[nxt][i] = nd;
    __syncthreads();
    cur = nxt;
  }

  out[g] = D[cur][i] / B[cur][i];
}

extern "C" void kernel_launch(void* const* d_in, const int* in_sizes, int n_in,
                              void* d_out, int out_size, void* d_ws, size_t ws_size,
                              hipStream_t stream) {
  const float* x      = (const float*)d_in[0];
  const float* w_comp = (const float*)d_in[1];
  float* out = (float*)d_out;

  float* mu_ws  = (float*)d_ws;
  float* sig_ws = mu_ws + ROWS;

  gaus_fit_kernel<<<ROWS / 16, 256, 0, stream>>>(x, mu_ws, sig_ws);
  pcr_solve_kernel<<<BN, XLEN, 0, stream>>>(mu_ws, sig_ws, w_comp, out);
}

// Round 24
// 24.268 us; speedup vs baseline: 1.0974x; 1.0029x over previous
//
#include <hip/hip_runtime.h>
#include <hip/hip_bf16.h>
#include <math.h>

#define BN 32
#define XLEN 1024
#define COLS 512
#define ROWS (BN * XLEN)   // 32768
#define STAB 1e-15

typedef float v2f __attribute__((ext_vector_type(2)));

// hardware transcendentals via AMDGCN builtins (glibc-collision-free):
//   HW_EXP2(x) = v_exp_f32 = 2^x ;  HW_LOG2(x) = v_log_f32 = log2(x)
#define HW_EXP2(x) __builtin_amdgcn_exp2f(x)
#define HW_LOG2(x) __builtin_amdgcn_logf(x)
#define HW_RCP(x)  __builtin_amdgcn_rcpf(x)

// ---------------------------------------------------------------------------
// DPP rotate helpers: row_ror:N rotates within each 16-lane row on the VALU
// pipe (no LDS traffic). Rotate-reduce over N=8,4,2,1 gives every lane of a
// 16-lane group the full group reduction. DPP ctrl: ROW_ROR_N = 0x120 + N.
// ---------------------------------------------------------------------------
template <int CTRL>
__device__ __forceinline__ float dpp_rot_f32(float v) {
  return __int_as_float(__builtin_amdgcn_mov_dpp(
      __float_as_int(v), CTRL, 0xF, 0xF, false));
}
template <int CTRL>
__device__ __forceinline__ double dpp_rot_f64(double v) {
  const unsigned long long u = __double_as_longlong(v);
  const int lo = __builtin_amdgcn_mov_dpp((int)(u & 0xFFFFFFFFull),
                                          CTRL, 0xF, 0xF, false);
  const int hi = __builtin_amdgcn_mov_dpp((int)(u >> 32),
                                          CTRL, 0xF, 0xF, false);
  return __longlong_as_double(((unsigned long long)(unsigned)hi << 32) |
                              (unsigned)lo);
}
#define ROR8 0x128
#define ROR4 0x124
#define ROR2 0x122
#define ROR1 0x121

__device__ __forceinline__ float dpp_max16_f32(float v) {
  v = fmaxf(v, dpp_rot_f32<ROR8>(v));
  v = fmaxf(v, dpp_rot_f32<ROR4>(v));
  v = fmaxf(v, dpp_rot_f32<ROR2>(v));
  v = fmaxf(v, dpp_rot_f32<ROR1>(v));
  return v;
}
__device__ __forceinline__ float dpp_min16_f32(float v) {
  v = fminf(v, dpp_rot_f32<ROR8>(v));
  v = fminf(v, dpp_rot_f32<ROR4>(v));
  v = fminf(v, dpp_rot_f32<ROR2>(v));
  v = fminf(v, dpp_rot_f32<ROR1>(v));
  return v;
}
__device__ __forceinline__ double dpp_sum16_f64(double v) {
  v += dpp_rot_f64<ROR8>(v);
  v += dpp_rot_f64<ROR4>(v);
  v += dpp_rot_f64<ROR2>(v);
  v += dpp_rot_f64<ROR1>(v);
  return v;
}

// ---------------------------------------------------------------------------
// Kernel 1: softmax -> min-max normalize -> weighted Gaussian fit.
// KEY ALGEBRA: the softmax denominator S cancels exactly in the
// normalized value:  pn = (e/S - emin/S) / ((1 - emin)/S) + 0.001
//                       = (e - emin) / (1 - emin) + 0.001.
// So S is never computed: no sum accumulation, no S-reduce, no divide by S.
// Single compute pass: e = exp2(fma(x,log2e,-mxs)); pn = fma(e, CA, CB) with
// CA = 1/(1-emin), CB = fma(-emin, CA, 0.001); l2 = v_log_f32(pn); moments.
// Error class: 1-2 ulp on pn vs the S-form (same family as the CA/CB fusion
// accepted since round 10; dominant error remains f32 moment accumulation).
// Structure: 4 rows/wave, 16 lanes/row, 16 packed pairs/lane, 4 waves per
// 256-thread block, grid 2048; all reductions via DPP row_ror (round 21).
// PRECISION NOTE (round-14 lesson): cross-lane reduction tree MUST be f64.
// FUSION NOTE (round-18): do not fuse PCR (regalloc collapse -> spill, 4x).
// PIPELINE NOTE (round-20): 2-deep row pipelining costs occupancy, -5%.
// ---------------------------------------------------------------------------
__global__ __launch_bounds__(256) void gaus_fit_kernel(
    const float* __restrict__ x, float* __restrict__ mu_out,
    float* __restrict__ sig_out) {
  const int lane = threadIdx.x & 63;
  const int wid  = threadIdx.x >> 6;   // wave 0..3 in block
  const int sub  = lane & 15;          // lane within row-group
  const int row  = blockIdx.x * 16 + wid * 4 + (lane >> 4);

  // Each lane: 16 v2f loads (adjacent pairs merge to dwordx4); pair k=2j+h
  // covers cols 64*j + 4*sub + {2h, 2h+1}.
  const v2f* rp2 = (const v2f*)(x + (size_t)row * COLS);
  v2f ve[16];
#pragma unroll
  for (int j = 0; j < 8; ++j) {
    ve[2 * j]     = rp2[32 * j + 2 * sub];
    ve[2 * j + 1] = rp2[32 * j + 2 * sub + 1];
  }

  // packed min/max of raw x, then component + 16-lane DPP reduce
  v2f mx2 = ve[0], xn2 = ve[0];
#pragma unroll
  for (int k = 1; k < 16; ++k) {
    mx2 = __builtin_elementwise_max(mx2, ve[k]);
    xn2 = __builtin_elementwise_min(xn2, ve[k]);
  }
  const float mx = dpp_max16_f32(fmaxf(mx2.x, mx2.y));
  const float xn = dpp_min16_f32(fminf(xn2.x, xn2.y));

  // normalize constants (S-free): emin = exp(xn - mx); emax = exp(0) = 1
  const float LOG2E = 1.44269504089f;
  const float mxs  = mx * LOG2E;
  const float emin = HW_EXP2(fmaf(xn, LOG2E, -mxs));
  const float CA   = 1.0f / (1.0f - emin);
  const float CB   = fmaf(-emin, CA, 0.001f);
  const v2f L2E2 = {LOG2E, LOG2E};
  const v2f NMXS = {-mxs, -mxs};
  const v2f CA2 = {CA, CA}, CB2 = {CB, CB};

  // SINGLE pass: exp2 -> pn -> log2 -> packed f32 moment accumulation.
  // xh per pair = bb + compile-time-constant offset (exact), no serial chain.
  const float bb = (float)(4 * sub) * (1.0f / 512.0f);
  v2f u0 = {0, 0}, u1 = {0, 0}, u2 = {0, 0}, u3 = {0, 0}, u4 = {0, 0};
  v2f w0 = {0, 0}, w1 = {0, 0}, w2 = {0, 0};

#define GF_PAIR(j, h)                                                         \
  {                                                                           \
    const int   k   = 2 * (j) + (h);                                          \
    const float off = (float)(64 * (j) + 2 * (h)) * (1.0f / 512.0f);          \
    const v2f xh = {bb + off, bb + off + 0.001953125f};                       \
    const v2f xs = __builtin_elementwise_fma(ve[k], L2E2, NMXS);              \
    v2f e;                                                                    \
    e.x = HW_EXP2(xs.x);                                                      \
    e.y = HW_EXP2(xs.y);                                                      \
    const v2f pn = __builtin_elementwise_fma(e, CA2, CB2);                    \
    v2f l2;                                                                   \
    l2.x = HW_LOG2(pn.x);                                                     \
    l2.y = HW_LOG2(pn.y);                                                     \
    const v2f y2  = pn * pn;                                                  \
    const v2f y2l = y2 * l2;                                                  \
    const v2f x2  = xh * xh;                                                  \
    const v2f x3  = x2 * xh;                                                  \
    const v2f x4  = x2 * x2;                                                  \
    u0 += y2;                                                                 \
    u1 = __builtin_elementwise_fma(xh, y2, u1);                               \
    u2 = __builtin_elementwise_fma(x2, y2, u2);                               \
    u3 = __builtin_elementwise_fma(x3, y2, u3);                               \
    u4 = __builtin_elementwise_fma(x4, y2, u4);                               \
    w0 += y2l;                                                                \
    w1 = __builtin_elementwise_fma(xh, y2l, w1);                              \
    w2 = __builtin_elementwise_fma(x2, y2l, w2);                              \
  }

#pragma unroll
  for (int j = 0; j < 8; ++j) {
    GF_PAIR(j, 0)
    GF_PAIR(j, 1)
  }
#undef GF_PAIR

  // per-lane exact f64 hadd, then 16-lane DPP rotate-reduce in f64
  // (f64 REQUIRED here — see precision note above)
  const double d0 = dpp_sum16_f64((double)u0.x + (double)u0.y);
  const double d1 = dpp_sum16_f64((double)u1.x + (double)u1.y);
  const double d2 = dpp_sum16_f64((double)u2.x + (double)u2.y);
  const double d3 = dpp_sum16_f64((double)u3.x + (double)u3.y);
  const double d4 = dpp_sum16_f64((double)u4.x + (double)u4.y);
  const double e0 = dpp_sum16_f64((double)w0.x + (double)w0.y);
  const double e1 = dpp_sum16_f64((double)w1.x + (double)w1.y);
  const double e2 = dpp_sum16_f64((double)w2.x + (double)w2.y);

  if (sub == 0) {   // lanes 0,16,32,48 — one per row
    const double LN2D = 0.6931471805599453;
    // unscale by exact 512^k; apply ln2 to the log2-sums (one rounding each)
    const double s_y2    = d0;
    const double s_xy2   = d1 * 512.0;
    const double s_x2y2  = d2 * 262144.0;            // 512^2
    const double s_x3y2  = d3 * 134217728.0;         // 512^3
    const double s_x4y2  = d4 * 68719476736.0;       // 512^4
    const double s_y2l   = e0 * LN2D;
    const double s_xy2l  = (e1 * 512.0) * LN2D;
    const double s_x2y2l = (e2 * 262144.0) * LN2D;
    const double A2 = s_x2y2 * s_x2y2;
    double b_num = A2 * s_xy2l - s_y2 * s_x4y2 * s_xy2l
                 + s_xy2 * s_x4y2 * s_y2l + s_y2 * s_x3y2 * s_x2y2l
                 - s_x2y2 * s_x3y2 * s_y2l - s_xy2 * s_x2y2 * s_x2y2l;
    double c_num = s_x2y2l * s_xy2 * s_xy2 - s_xy2l * s_xy2 * s_x2y2
                 - s_x3y2 * s_y2l * s_xy2 + s_y2l * A2
                 - s_y2 * s_x2y2l * s_x2y2 + s_y2 * s_x3y2 * s_xy2l;
    if (fabs(c_num) < STAB) {
      c_num = (c_num > 0.0) ? STAB : ((c_num < 0.0) ? -STAB : 0.0);
    }
    const double mu = -b_num / (2.0 * c_num);
    const double c_din = s_x4y2 * s_xy2 * s_xy2
                       - 2.0 * s_xy2 * s_x2y2 * s_x3y2 + s_x2y2 * A2
                       - s_y2 * s_x4y2 * s_x2y2 + s_y2 * s_x3y2 * s_x3y2;
    double sigma = -0.5 * c_din / c_num;
    if (sigma < 1.0) sigma = 1.0;  // NaN stays NaN, matching jnp.where
    mu_out[row]  = (float)mu;
    sig_out[row] = (float)sigma;
  }
}

// ---------------------------------------------------------------------------
// Kernel 2: per-batch tridiagonal solve via parallel cyclic reduction, f32.
// (Byte-identical to round 21, which passed.)
// ---------------------------------------------------------------------------
__global__ __launch_bounds__(1024) void pcr_solve_kernel(
    const float* __restrict__ mu, const float* __restrict__ sigma,
    const float* __restrict__ w_comp, float* __restrict__ out) {
  __shared__ float A[2][XLEN], B[2][XLEN], C[2][XLEN], D[2][XLEN];
  const int i = threadIdx.x;
  const int g = blockIdx.x * XLEN + i;

  const float w = w_comp[0];
  const float offf  = -2.0f * w;
  const float mainw = (i == 0 || i == XLEN - 1) ? (2.0f * w) : (4.0f * w);
  const float sr = 1.0f / sigma[g];      // f32, matches reference
  const float bf = mainw + sr;           // f32 diag entry
  const float df = mu[g] * sr;           // f32 rhs

  A[0][i] = (i == 0) ? 0.0f : offf;
  C[0][i] = (i == XLEN - 1) ? 0.0f : offf;
  B[0][i] = bf;
  D[0][i] = df;
  __syncthreads();

  int cur = 0;
  for (int s = 1; s < XLEN; s <<= 1) {
    const float ai = A[cur][i], bi = B[cur][i], ci = C[cur][i], di = D[cur][i];
    float am = 0.0f, cm = 0.0f, dm = 0.0f, rm = 0.0f;
    float ap = 0.0f, cp = 0.0f, dp = 0.0f, rp = 0.0f;
    if (i >= s) {
      am = A[cur][i - s]; cm = C[cur][i - s]; dm = D[cur][i - s];
      rm = HW_RCP(B[cur][i - s]);
    }
    if (i + s < XLEN) {
      ap = A[cur][i + s]; cp = C[cur][i + s]; dp = D[cur][i + s];
      rp = HW_RCP(B[cur][i + s]);
    }
    const float k1 = ai * rm;   // rm/rp are 0 when guarded out
    const float k2 = ci * rp;
    const float nb = bi - k1 * cm - k2 * ap;
    const float nd = di - k1 * dm - k2 * dp;
    const int nxt = cur ^ 1;
    A[nxt][i] = -k1 * am;
    C[nxt][i] = -k2 * cp;
    B[nxt][i] = nb;
    D[nxt][i] = nd;
    __syncthreads();
    cur = nxt;
  }

  out[g] = D[cur][i] / B[cur][i];
}

extern "C" void kernel_launch(void* const* d_in, const int* in_sizes, int n_in,
                              void* d_out, int out_size, void* d_ws, size_t ws_size,
                              hipStream_t stream) {
  const float* x      = (const float*)d_in[0];
  const float* w_comp = (const float*)d_in[1];
  float* out = (float*)d_out;

  float* mu_ws  = (float*)d_ws;
  float* sig_ws = mu_ws + ROWS;

  gaus_fit_kernel<<<ROWS / 16, 256, 0, stream>>>(x, mu_ws, sig_ws);
  pcr_solve_kernel<<<BN, XLEN, 0, stream>>>(mu_ws, sig_ws, w_comp, out);
}